// Round 2
// baseline (2193.541 us; speedup 1.0000x reference)
//
#include <hip/hip_runtime.h>

#define S    4096
#define CH   256
#define NB   8

#define QT   32
#define KT   512
#define CKC  32

#define NEG_INF (-3.402823466e38f)

// ---------------------------------------------------------------------------
// out[:, 0:512] = input  (per-batch contiguous copy, float4 vectorized)
__global__ void copy_fl(const float* __restrict__ x, float* __restrict__ out) {
    int i = blockIdx.x * 256 + threadIdx.x;          // float4 index
    const int per_b = 512 * S / 4;                   // 524288
    int b = i / per_b;
    int r = i - b * per_b;
    const float4* src = (const float4*)x;
    float4* dst = (float4*)out;
    dst[(size_t)b * (768 * S / 4) + r] = src[(size_t)b * per_b + r];
}

// ---------------------------------------------------------------------------
// order-preserving compaction: qlist = {s : flag[s]==1}, klist = {s : flag[s]==0}
__global__ void compact(const int* __restrict__ flag, int* __restrict__ cnts,
                        int* __restrict__ qlist, int* __restrict__ klist) {
    __shared__ int sq[256], sk[256];
    int t = threadIdx.x;
    int base = t * 16;
    int f[16];
    int nq = 0, nk = 0;
    #pragma unroll
    for (int i = 0; i < 16; ++i) {
        f[i] = flag[base + i];
        nq += (f[i] == 1);
        nk += (f[i] == 0);
    }
    sq[t] = nq; sk[t] = nk;
    __syncthreads();
    for (int off = 1; off < 256; off <<= 1) {
        int vq = sq[t], vk = sk[t];
        int aq = (t >= off) ? sq[t - off] : 0;
        int ak = (t >= off) ? sk[t - off] : 0;
        __syncthreads();
        sq[t] = vq + aq; sk[t] = vk + ak;
        __syncthreads();
    }
    int pq = sq[t] - nq;
    int pk = sk[t] - nk;
    #pragma unroll
    for (int i = 0; i < 16; ++i) {
        if (f[i] == 1)      qlist[pq++] = base + i;
        else                klist[pk++] = base + i;
    }
    if (t == 255) { cnts[0] = sq[255]; cnts[1] = sk[255]; }
}

// ---------------------------------------------------------------------------
// invn[b][k] = 1 / max(||l[b,k,:]||, 1e-12)
__global__ void invnorm_k(const float* __restrict__ x, float* __restrict__ invn) {
    int k = blockIdx.x * 256 + threadIdx.x;
    int b = blockIdx.y;
    const float* base = x + ((size_t)b * 512 + 256) * S + k;
    float acc = 0.f;
    #pragma unroll 8
    for (int c = 0; c < CH; ++c) {
        float v = base[(size_t)c * S];
        acc += v * v;
    }
    invn[b * S + k] = 1.0f / fmaxf(sqrtf(acc), 1e-12f);
}

// ---------------------------------------------------------------------------
// per (b, 32-q tile): argmax over active k of dot(f[q], l_norm[k])
// 256 threads; each thread: 8 q rows x 8 k cols register tile.
__launch_bounds__(256)
__global__ void argmax_gemm(const float* __restrict__ x,
                            const int*  __restrict__ cnts,
                            const int*  __restrict__ qlist,
                            const int*  __restrict__ klist,
                            const float* __restrict__ invn,
                            int* __restrict__ idxb) {
    __shared__ float Fs[CKC][QT];      // 4 KB
    __shared__ float Ls[CKC][KT];      // 64 KB
    __shared__ int   qi_s[QT];
    __shared__ int   kidx_s[KT];       // 2 KB

    const int Aq = cnts[0];
    const int Ak = cnts[1];
    const int b  = blockIdx.y;
    const int q0 = blockIdx.x * QT;
    if (q0 >= Aq) return;

    const int tid = threadIdx.x;
    const int tq  = tid >> 6;    // 0..3  (wave index; uniform within wave)
    const int tk  = tid & 63;    // 0..63

    const float* Fm   = x + (size_t)b * 512 * S;     // former, [c][s]
    const float* Lm   = Fm + (size_t)CH * S;         // latter, [c][s]
    const float* invb = invn + b * S;

    if (tid < QT) {
        int qp = q0 + tid;
        qi_s[tid] = qlist[(qp < Aq) ? qp : (Aq - 1)];
    }
    __syncthreads();

    float rm[8]; int ri[8];
    #pragma unroll
    for (int i = 0; i < 8; ++i) { rm[i] = NEG_INF; ri[i] = 0; }

    const int nkt = (Ak + KT - 1) / KT;
    for (int kt = 0; kt < nkt; ++kt) {
        __syncthreads();     // prev epilogue done reading kidx_s

        // per-thread k slots tid and tid+256 of this k-tile
        int kp0 = kt * KT + tid;
        int kp1 = kp0 + 256;
        int kk0 = (kp0 < Ak) ? klist[kp0] : -1;
        int kk1 = (kp1 < Ak) ? klist[kp1] : -1;
        float in0 = (kk0 >= 0) ? invb[kk0] : 0.f;
        float in1 = (kk1 >= 0) ? invb[kk1] : 0.f;
        kidx_s[tid]       = kk0;
        kidx_s[tid + 256] = kk1;

        float acc[8][8];
        #pragma unroll
        for (int a = 0; a < 8; ++a)
            #pragma unroll
            for (int c = 0; c < 8; ++c) acc[a][c] = 0.f;

        for (int c0 = 0; c0 < CH; c0 += CKC) {
            __syncthreads();   // prev compute done with Ls; kidx_s visible

            // stage Fs: 32x32, 4 elems/thread
            #pragma unroll
            for (int p = 0; p < 4; ++p) {
                int e  = p * 256 + tid;
                int cc = e >> 5;
                int i  = e & 31;
                Fs[cc][i] = Fm[(size_t)(c0 + cc) * S + qi_s[i]];
            }
            // stage Ls: per-thread column walk (thread owns k slots tid, tid+256)
            const float* lp0 = Lm + (size_t)c0 * S + ((kk0 >= 0) ? kk0 : 0);
            const float* lp1 = Lm + (size_t)c0 * S + ((kk1 >= 0) ? kk1 : 0);
            #pragma unroll 8
            for (int cc = 0; cc < CKC; ++cc) {
                Ls[cc][tid]       = (kk0 >= 0) ? lp0[(size_t)cc * S] * in0 : 0.f;
                Ls[cc][tid + 256] = (kk1 >= 0) ? lp1[(size_t)cc * S] * in1 : 0.f;
            }
            __syncthreads();

            #pragma unroll
            for (int cc = 0; cc < CKC; ++cc) {
                const float4 fa = *(const float4*)&Fs[cc][tq * 4];        // wave-uniform
                const float4 fb = *(const float4*)&Fs[cc][16 + tq * 4];   // wave-uniform
                const float4 la = *(const float4*)&Ls[cc][tk * 4];
                const float4 lb = *(const float4*)&Ls[cc][256 + tk * 4];
                float av[8] = { fa.x, fa.y, fa.z, fa.w, fb.x, fb.y, fb.z, fb.w };
                float bv[8] = { la.x, la.y, la.z, la.w, lb.x, lb.y, lb.z, lb.w };
                #pragma unroll
                for (int qq = 0; qq < 8; ++qq)
                    #pragma unroll
                    for (int jj = 0; jj < 8; ++jj)
                        acc[qq][jj] += av[qq] * bv[jj];
            }
        }

        // epilogue: fold this k-tile into running (max, idx); ascending k order
        #pragma unroll
        for (int jj = 0; jj < 8; ++jj) {
            int slot = (jj < 4) ? (tk * 4 + jj) : (256 + tk * 4 + (jj - 4));
            int kk = kidx_s[slot];
            if (kk >= 0) {
                #pragma unroll
                for (int qq = 0; qq < 8; ++qq) {
                    float sv = acc[qq][jj];
                    if (sv > rm[qq]) { rm[qq] = sv; ri[qq] = kk; }
                    else if (sv == rm[qq] && kk < ri[qq]) { ri[qq] = kk; }
                }
            }
        }
    }

    // reduce across the 64 lanes of this wave (all share the same 8 q rows)
    #pragma unroll
    for (int qq = 0; qq < 8; ++qq) {
        float m = rm[qq]; int id = ri[qq];
        #pragma unroll
        for (int off = 32; off; off >>= 1) {
            float om = __shfl_xor(m, off, 64);
            int   oi = __shfl_xor(id, off, 64);
            if (om > m || (om == m && oi < id)) { m = om; id = oi; }
        }
        if (tk == 0) {
            int row = (qq < 4) ? (tq * 4 + qq) : (16 + tq * 4 + (qq - 4));
            if (q0 + row < Aq) idxb[b * S + qi_s[row]] = id;
        }
    }
}

// ---------------------------------------------------------------------------
// out[b][512+c][q] = flag[q]==1 ? latter[b][c][idx[b][q]] : 0
__global__ void scatter_k(const float* __restrict__ x, const int* __restrict__ flag,
                          const int* __restrict__ idxb, float* __restrict__ out) {
    int e = blockIdx.x * 256 + threadIdx.x;   // 8 * 256 * 4096 total
    int q = e & (S - 1);
    int c = (e >> 12) & 255;
    int b = e >> 20;
    float v = 0.f;
    if (flag[q] == 1) {
        int id = idxb[b * S + q];
        v = x[((size_t)b * 512 + 256 + c) * S + id];
    }
    out[((size_t)b * 768 + 512 + c) * S + q] = v;
}

// ---------------------------------------------------------------------------
extern "C" void kernel_launch(void* const* d_in, const int* in_sizes, int n_in,
                              void* d_out, int out_size, void* d_ws, size_t ws_size,
                              hipStream_t stream) {
    const float* x    = (const float*)d_in[0];
    const int*   flag = (const int*)d_in[2];
    float*       out  = (float*)d_out;

    char* ws = (char*)d_ws;
    int*   cnts  = (int*)ws;                                  // 2 ints
    int*   qlist = (int*)(ws + 64);                           // 4096 ints
    int*   klist = (int*)(ws + 64 + 16384);                   // 4096 ints
    float* invn  = (float*)(ws + 64 + 32768);                 // 8*4096 floats
    int*   idxb  = (int*)(ws + 64 + 32768 + 131072);          // 8*4096 ints

    hipLaunchKernelGGL(copy_fl,     dim3((NB * 512 * S / 4) / 256), dim3(256), 0, stream, x, out);
    hipLaunchKernelGGL(compact,     dim3(1),                        dim3(256), 0, stream, flag, cnts, qlist, klist);
    hipLaunchKernelGGL(invnorm_k,   dim3(S / 256, NB),              dim3(256), 0, stream, x, invn);
    hipLaunchKernelGGL(argmax_gemm, dim3(S / QT, NB),               dim3(256), 0, stream, x, cnts, qlist, klist, invn, idxb);
    hipLaunchKernelGGL(scatter_k,   dim3((NB * CH * S) / 256),      dim3(256), 0, stream, x, flag, idxb, out);
}

// Round 3
// 366.943 us; speedup vs baseline: 5.9779x; 5.9779x over previous
//
#include <hip/hip_runtime.h>

#define S    4096
#define CH   256
#define NB   8

#define BM   64
#define BN   128
#define CK   16
#define KSPLIT 4

#define NEG_INF (-3.402823466e38f)

// ---------------------------------------------------------------------------
// out[:, 0:512] = input  (per-batch contiguous copy, float4 vectorized)
__global__ void copy_fl(const float* __restrict__ x, float* __restrict__ out) {
    int i = blockIdx.x * 256 + threadIdx.x;          // float4 index
    const int per_b = 512 * S / 4;
    int b = i / per_b;
    int r = i - b * per_b;
    const float4* src = (const float4*)x;
    float4* dst = (float4*)out;
    dst[(size_t)b * (768 * S / 4) + r] = src[(size_t)b * per_b + r];
}

// ---------------------------------------------------------------------------
// order-preserving compaction: qlist = {s : flag[s]==1}, klist = {s : flag[s]==0}
__global__ void compact(const int* __restrict__ flag, int* __restrict__ cnts,
                        int* __restrict__ qlist, int* __restrict__ klist) {
    __shared__ int sq[256], sk[256];
    int t = threadIdx.x;
    int base = t * 16;
    int f[16];
    int nq = 0, nk = 0;
    #pragma unroll
    for (int i = 0; i < 16; ++i) {
        f[i] = flag[base + i];
        nq += (f[i] == 1);
        nk += (f[i] == 0);
    }
    sq[t] = nq; sk[t] = nk;
    __syncthreads();
    for (int off = 1; off < 256; off <<= 1) {
        int vq = sq[t], vk = sk[t];
        int aq = (t >= off) ? sq[t - off] : 0;
        int ak = (t >= off) ? sk[t - off] : 0;
        __syncthreads();
        sq[t] = vq + aq; sk[t] = vk + ak;
        __syncthreads();
    }
    int pq = sq[t] - nq;
    int pk = sk[t] - nk;
    #pragma unroll
    for (int i = 0; i < 16; ++i) {
        if (f[i] == 1)      qlist[pq++] = base + i;
        else                klist[pk++] = base + i;
    }
    if (t == 255) { cnts[0] = sq[255]; cnts[1] = sk[255]; }
}

// ---------------------------------------------------------------------------
// invn[b][k] = 1 / max(||l[b,k,:]||, 1e-12)
__global__ void invnorm_k(const float* __restrict__ x, float* __restrict__ invn) {
    int k = blockIdx.x * 256 + threadIdx.x;
    int b = blockIdx.y;
    const float* base = x + ((size_t)b * 512 + 256) * S + k;
    float acc = 0.f;
    #pragma unroll 8
    for (int c = 0; c < CH; ++c) {
        float v = base[(size_t)c * S];
        acc += v * v;
    }
    invn[(b << 12) + k] = 1.0f / fmaxf(sqrtf(acc), 1e-12f);
}

// ---------------------------------------------------------------------------
// pack normalized active-k columns of latter into dense [c][j] (j = compact k),
// stored in the out[:,512:768] slab (scratch until scatter_k overwrites it).
__global__ void pack_ln(const float* __restrict__ x, const int* __restrict__ cnts,
                        const int* __restrict__ klist, const float* __restrict__ invn,
                        float* __restrict__ out) {
    int j = blockIdx.x * 256 + threadIdx.x;
    int b = blockIdx.z;
    int Ak = cnts[1];
    int kk = -1; float w = 0.f;
    if (j < Ak) { kk = klist[j]; w = invn[(b << 12) + kk]; }
    const float* Lm = x + ((size_t)b * 512 + 256) * S;
    float* dst = out + ((size_t)b * 768 + 512) * S;
    #pragma unroll
    for (int c8 = 0; c8 < 8; ++c8) {
        int c = blockIdx.y * 8 + c8;
        dst[(size_t)c * S + j] = (kk >= 0) ? Lm[(size_t)c * S + kk] * w : 0.f;
    }
}

// ---------------------------------------------------------------------------
// dense argmax GEMM: per (b, 64-q tile, k-split) block; BM=64 x BN=128 tiles,
// CK=16 c-chunks, 4q x 8k per-thread register tile. Partial (max,idx) per split.
__launch_bounds__(256, 4)
__global__ void argmax_gemm(const float* __restrict__ x,
                            const float* __restrict__ lnbase,   // == out
                            const int*  __restrict__ cnts,
                            const int*  __restrict__ qlist,
                            const int*  __restrict__ klist,
                            float* __restrict__ pmax,
                            int*   __restrict__ pidx) {
    __shared__ float Fs[CK][BM];     // 4 KB
    __shared__ float Ls[CK][BN];     // 8 KB
    __shared__ int   qi_s[BM];

    const int Aq    = cnts[0];
    const int Ak    = cnts[1];
    const int b     = blockIdx.y;
    const int split = blockIdx.x & (KSPLIT - 1);
    const int q0    = (blockIdx.x >> 2) * BM;
    if (q0 >= Aq) return;

    const int tid = threadIdx.x;
    const int tx  = tid & 15;       // k-group: cols tx*4.. and 64+tx*4..
    const int ty  = tid >> 4;       // q-group: rows ty*4..ty*4+3

    const float* Fm  = x + (size_t)b * 512 * S;                 // former [c][s]
    const float* Lnb = lnbase + ((size_t)b * 768 + 512) * S;    // packed L [c][j]

    if (tid < BM) {
        int qp = q0 + tid;
        qi_s[tid] = qlist[(qp < Aq) ? qp : (Aq - 1)];
    }
    __syncthreads();

    const int nkt = (Ak + BN - 1) / BN;
    const int kt0 = (nkt * split) / KSPLIT;
    const int kt1 = (nkt * (split + 1)) / KSPLIT;

    float rm[4]; int ri[4];
    #pragma unroll
    for (int i = 0; i < 4; ++i) { rm[i] = NEG_INF; ri[i] = 0; }

    for (int kt = kt0; kt < kt1; ++kt) {
        const int kbase = kt * BN;

        float acc[4][8];
        #pragma unroll
        for (int a = 0; a < 4; ++a)
            #pragma unroll
            for (int c = 0; c < 8; ++c) acc[a][c] = 0.f;

        for (int c0 = 0; c0 < CH; c0 += CK) {
            __syncthreads();        // previous chunk's compute done with Fs/Ls
            // stage Fs[cc][i] = Fm[c0+cc][qi[i]]   (1024 floats, gather)
            #pragma unroll
            for (int p = 0; p < 4; ++p) {
                int e  = p * 256 + tid;
                int cc = e >> 6;
                int i  = e & 63;
                Fs[cc][i] = Fm[(size_t)(c0 + cc) * S + qi_s[i]];
            }
            // stage Ls[cc][*] from packed Ln (2048 floats, float4 coalesced)
            #pragma unroll
            for (int p = 0; p < 2; ++p) {
                int e4 = p * 256 + tid;
                int cc = e4 >> 5;
                int x4 = (e4 & 31) << 2;
                *(float4*)&Ls[cc][x4] =
                    *(const float4*)&Lnb[(size_t)(c0 + cc) * S + kbase + x4];
            }
            __syncthreads();

            #pragma unroll
            for (int cc = 0; cc < CK; ++cc) {
                const float4 a4 = *(const float4*)&Fs[cc][ty * 4];
                const float4 b0 = *(const float4*)&Ls[cc][tx * 4];
                const float4 b1 = *(const float4*)&Ls[cc][64 + tx * 4];
                float av[4] = { a4.x, a4.y, a4.z, a4.w };
                float bv[8] = { b0.x, b0.y, b0.z, b0.w, b1.x, b1.y, b1.z, b1.w };
                #pragma unroll
                for (int qq = 0; qq < 4; ++qq)
                    #pragma unroll
                    for (int jj = 0; jj < 8; ++jj)
                        acc[qq][jj] += av[qq] * bv[jj];
            }
        }

        // epilogue: fold k-tile into running (max, idx); ascending-k order
        #pragma unroll
        for (int jj = 0; jj < 8; ++jj) {
            int col = (jj < 4) ? (tx * 4 + jj) : (64 + tx * 4 + (jj - 4));
            int kp  = kbase + col;
            if (kp < Ak) {
                int kk = klist[kp];
                #pragma unroll
                for (int qq = 0; qq < 4; ++qq) {
                    float sv = acc[qq][jj];
                    if (sv > rm[qq]) { rm[qq] = sv; ri[qq] = kk; }
                    else if (sv == rm[qq] && kk < ri[qq]) { ri[qq] = kk; }
                }
            }
        }
    }

    // reduce across the 16 lanes sharing a q-row group (aligned 16-lane chunks)
    #pragma unroll
    for (int qq = 0; qq < 4; ++qq) {
        float m = rm[qq]; int id = ri[qq];
        #pragma unroll
        for (int off = 8; off; off >>= 1) {
            float om = __shfl_xor(m, off, 64);
            int   oi = __shfl_xor(id, off, 64);
            if (om > m || (om == m && oi < id)) { m = om; id = oi; }
        }
        if (tx == 0) {
            int qp = q0 + ty * 4 + qq;
            if (qp < Aq) {
                pmax[((size_t)((b << 12) + qp)) * KSPLIT + split] = m;
                pidx[((size_t)((b << 12) + qp)) * KSPLIT + split] = id;
            }
        }
    }
}

// ---------------------------------------------------------------------------
// combine k-split partials -> idxb[b][q]  (strict > keeps lowest split = smallest k)
__global__ void combine(const int* __restrict__ cnts, const int* __restrict__ qlist,
                        const float* __restrict__ pmax, const int* __restrict__ pidx,
                        int* __restrict__ idxb) {
    int qp = blockIdx.x * 256 + threadIdx.x;
    int b  = blockIdx.y;
    if (qp >= cnts[0]) return;
    size_t base = (size_t)((b << 12) + qp) * KSPLIT;
    float m = pmax[base]; int id = pidx[base];
    #pragma unroll
    for (int s = 1; s < KSPLIT; ++s) {
        float om = pmax[base + s]; int oi = pidx[base + s];
        if (om > m) { m = om; id = oi; }
    }
    idxb[(b << 12) + qlist[qp]] = id;
}

// ---------------------------------------------------------------------------
// out[b][512+c][q] = flag[q]==1 ? latter[b][c][idx[b][q]] : 0
__global__ void scatter_k(const float* __restrict__ x, const int* __restrict__ flag,
                          const int* __restrict__ idxb, float* __restrict__ out) {
    int e = blockIdx.x * 256 + threadIdx.x;
    int q = e & (S - 1);
    int c = (e >> 12) & 255;
    int b = e >> 20;
    float v = 0.f;
    if (flag[q] == 1) {
        int id = idxb[(b << 12) + q];
        v = x[((size_t)b * 512 + 256 + c) * S + id];
    }
    out[((size_t)b * 768 + 512 + c) * S + q] = v;
}

// ---------------------------------------------------------------------------
extern "C" void kernel_launch(void* const* d_in, const int* in_sizes, int n_in,
                              void* d_out, int out_size, void* d_ws, size_t ws_size,
                              hipStream_t stream) {
    const float* x    = (const float*)d_in[0];
    const int*   flag = (const int*)d_in[2];
    float*       out  = (float*)d_out;

    char* ws = (char*)d_ws;
    int*   cnts  = (int*)(ws);                 // 2 ints
    int*   qlist = (int*)(ws + 1024);          // 16 KB
    int*   klist = (int*)(ws + 17408);         // 16 KB
    float* invn  = (float*)(ws + 33792);       // 128 KB
    int*   idxb  = (int*)(ws + 164864);        // 128 KB
    float* pmax  = (float*)(ws + 295936);      // 512 KB
    int*   pidx  = (int*)(ws + 820224);        // 512 KB

    hipLaunchKernelGGL(copy_fl,     dim3((NB * 512 * S / 4) / 256), dim3(256), 0, stream, x, out);
    hipLaunchKernelGGL(compact,     dim3(1),                        dim3(256), 0, stream, flag, cnts, qlist, klist);
    hipLaunchKernelGGL(invnorm_k,   dim3(S / 256, NB),              dim3(256), 0, stream, x, invn);
    hipLaunchKernelGGL(pack_ln,     dim3(S / 256, CH / 8, NB),      dim3(256), 0, stream, x, cnts, klist, invn, out);
    hipLaunchKernelGGL(argmax_gemm, dim3((S / BM) * KSPLIT, NB),    dim3(256), 0, stream,
                       x, out, cnts, qlist, klist, pmax, pidx);
    hipLaunchKernelGGL(combine,     dim3(S / 256, NB),              dim3(256), 0, stream, cnts, qlist, pmax, pidx, idxb);
    hipLaunchKernelGGL(scatter_k,   dim3((NB * CH * S) / 256),      dim3(256), 0, stream, x, flag, idxb, out);
}